// Round 12
// baseline (192.298 us; speedup 1.0000x reference)
//
#include <hip/hip_runtime.h>
#include <hip/hip_bf16.h>
#include <hip/hip_fp16.h>

// Problem constants: B=2, N=10000, M=320000, QD=KD=HD=256, NUM_HEADS=8, dh=32.
#define DHID 256
#define NHEAD 8
#define BATCH 2

typedef _Float16 h8 __attribute__((ext_vector_type(8)));
typedef float f4 __attribute__((ext_vector_type(4)));

// ---------------- P0: W transpose->fp16 (z=0,1) + zero seg (z=2) ----------
__global__ __launch_bounds__(256) void prep_kernel(
    const float* __restrict__ Wq, const float* __restrict__ Wk,
    _Float16* __restrict__ Wtq, _Float16* __restrict__ Wtk,
    float* __restrict__ seg, int segN)
{
    if (blockIdx.z == 2) {
        int idx = (blockIdx.x * 8 + blockIdx.y) * 256 + threadIdx.y * 32 + threadIdx.x;
        for (int i = idx; i < segN; i += 64 * 256) seg[i] = 0.f;
        return;
    }
    const float* W = blockIdx.z ? Wk : Wq;
    _Float16* Wt   = blockIdx.z ? Wtk : Wtq;
    __shared__ float tile[32][33];
    const int tx = threadIdx.x;   // 0..31
    const int ty = threadIdx.y;   // 0..7
    const int n0 = blockIdx.x * 32;
    const int k0 = blockIdx.y * 32;
#pragma unroll
    for (int j = 0; j < 32; j += 8)
        tile[ty + j][tx] = W[(size_t)(k0 + ty + j) * DHID + n0 + tx];
    __syncthreads();
#pragma unroll
    for (int j = 0; j < 32; j += 8)
        Wt[(size_t)(n0 + ty + j) * DHID + k0 + tx] = (_Float16)tile[tx][ty + j];
}

// ---------------- MFMA GEMM, A-stationary (round-5 winner, unchanged) -----
__global__ __launch_bounds__(256, 2) void gemm_mfma(
    const float* __restrict__ Xq, const float* __restrict__ Xk,
    const _Float16* __restrict__ Wtq, const _Float16* __restrict__ Wtk,
    _Float16* __restrict__ Qh, _Float16* __restrict__ Kh, int Mrows)
{
    const float* X       = blockIdx.z ? Xk : Xq;
    const _Float16* Wt   = blockIdx.z ? Wtk : Wtq;
    _Float16* C          = blockIdx.z ? Kh : Qh;

    __shared__ _Float16 As[64 * 256];   // 32 KB, [row][k] swizzled
    __shared__ _Float16 Bs[64 * 256];   // 32 KB, [n][k]   swizzled

    const int t    = threadIdx.x;
    const int lane = t & 63;
    const int wave = t >> 6;
    const int rowBase = blockIdx.x * 64;

#pragma unroll
    for (int i = 0; i < 8; ++i) {
        int idx = t + i * 256;          // 0..2047
        int row = idx >> 5;
        int c   = idx & 31;
        int grow = rowBase + row;
        f4 v0 = {0,0,0,0}, v1 = {0,0,0,0};
        if (grow < Mrows) {
            const float* p = X + (size_t)grow * DHID + c * 8;
            v0 = *(const f4*)p;
            v1 = *(const f4*)(p + 4);
        }
        h8 hv;
        hv[0]=(_Float16)v0[0]; hv[1]=(_Float16)v0[1]; hv[2]=(_Float16)v0[2]; hv[3]=(_Float16)v0[3];
        hv[4]=(_Float16)v1[0]; hv[5]=(_Float16)v1[1]; hv[6]=(_Float16)v1[2]; hv[7]=(_Float16)v1[3];
        int sc = c ^ (row & 7);
        *(h8*)&As[row * 256 + sc * 8] = hv;
    }

    const int ar   = wave * 16 + (lane & 15);
    const int quad = lane >> 4;

    for (int ct64 = 0; ct64 < 4; ++ct64) {
#pragma unroll
        for (int i = 0; i < 8; ++i) {
            int idx = t + i * 256;
            int n = idx >> 5;
            int c = idx & 31;
            h8 hv = *(const h8*)(Wt + (size_t)(ct64 * 64 + n) * DHID + c * 8);
            int sc = c ^ (n & 7);
            *(h8*)&Bs[n * 256 + sc * 8] = hv;
        }
        __syncthreads();

        f4 acc[4] = {{0,0,0,0},{0,0,0,0},{0,0,0,0},{0,0,0,0}};
#pragma unroll
        for (int kc = 0; kc < 8; ++kc) {            // K chunk of 32
            int ac = (kc * 4 + quad) ^ (ar & 7);
            h8 afrag = *(const h8*)&As[ar * 256 + ac * 8];
#pragma unroll
            for (int ct = 0; ct < 4; ++ct) {
                int bn = ct * 16 + (lane & 15);
                int bc = (kc * 4 + quad) ^ (bn & 7);
                h8 bfrag = *(const h8*)&Bs[bn * 256 + bc * 8];
                acc[ct] = __builtin_amdgcn_mfma_f32_16x16x32_f16(afrag, bfrag, acc[ct], 0, 0, 0);
            }
        }

#pragma unroll
        for (int ct = 0; ct < 4; ++ct) {
#pragma unroll
            for (int r = 0; r < 4; ++r) {
                int grow = rowBase + wave * 16 + quad * 4 + r;
                if (grow < Mrows)
                    C[(size_t)grow * DHID + ct64 * 64 + ct * 16 + (lane & 15)] = (_Float16)acc[ct][r];
            }
        }
        __syncthreads();
    }
}

// ---------------- Edge kernel (r11 layout) with edge-range offset ---------
// Split into two half-range dispatches so gemm/norm can surface in top-5
// (visibility floor drops 65 -> ~33 us). Logic identical to round 11.
__global__ __launch_bounds__(256, 6) void edge_kernel(
    const _Float16* __restrict__ Qh, const _Float16* __restrict__ Kh,
    const int* __restrict__ mask, float* __restrict__ out,
    float* __restrict__ seg, int M, int N, int eoff, int eend)
{
    const int lane = threadIdx.x & 63;
    const int wave = threadIdx.x >> 6;
    const int c    = lane & 31;     // 16B chunk within row (c*8 halves)
    const int half = lane >> 5;     // which edge of the pair
    const int h    = c >> 2;        // head of this chunk
    const long e0 = (long)eoff + ((long)blockIdx.x * 4 + wave) * 8;
    const int b = blockIdx.y;
    if (e0 >= eend) return;

    // lanes 0..7: src of edges e0..e0+7; lanes 8..15: dst
    int idxv = 0;
    {
        long le = e0 + (lane & 7);
        if (le >= eend) le = eend - 1;
        if (lane < 8)       idxv = mask[le];
        else if (lane < 16) idxv = mask[M + le];
    }

    const _Float16* Qb = Qh + (size_t)b * N * DHID;
    const _Float16* Kb = Kh + (size_t)b * N * DHID;

    int sidx[4], didx[4];
#pragma unroll
    for (int p = 0; p < 4; ++p) {
        sidx[p] = __shfl(idxv, p * 2 + half);
        didx[p] = __shfl(idxv, 8 + p * 2 + half);
    }

    // ---- load phase: 8 instrs, each 2 full rows contiguous (512B x 2) ----
    h8 qv[4], kv[4];
#pragma unroll
    for (int p = 0; p < 4; ++p) {
        qv[p] = *(const h8*)(Qb + (size_t)sidx[p] * DHID + c * 8);
        kv[p] = *(const h8*)(Kb + (size_t)didx[p] * DHID + c * 8);
    }

    // ---- compute + emit ----
#pragma unroll
    for (int p = 0; p < 4; ++p) {
        float s = 0.f;
#pragma unroll
        for (int u = 0; u < 8; ++u)
            s += (float)qv[p][u] * (float)kv[p][u];
        s += __shfl_xor(s, 1);
        s += __shfl_xor(s, 2);          // quad c&~3..c|3 now holds head sum
        float ev = expf(s * 0.0625f);   // 1/sqrt(256) = 1/16
        const long e = e0 + p * 2 + half;
        if ((c & 3) == 0 && e < eend) {
            __builtin_nontemporal_store(ev, &out[((size_t)b * M + e) * NHEAD + h]);
            atomicAdd(seg + ((size_t)b * N + sidx[p]) * NHEAD + h, ev);
        }
    }
}

// ---------------- Normalize: out = e / (seg[src] + 1e-16) -----------------
__global__ __launch_bounds__(256) void norm_kernel(
    const int* __restrict__ mask, const float* __restrict__ seg,
    float* __restrict__ out, int M, int N, int BM)
{
    int idx = blockIdx.x * 256 + threadIdx.x;   // idx = b*M + e
    if (idx >= BM) return;
    int b = idx / M;
    int e = idx - b * M;
    int src = mask[e];
    const f4* s4 = (const f4*)(seg + ((size_t)b * N + src) * NHEAD);
    f4 s0 = s4[0], s1 = s4[1];
    f4* o4 = (f4*)(out + (size_t)idx * NHEAD);
    f4 o0 = o4[0], o1 = o4[1];
    o0[0] *= __builtin_amdgcn_rcpf(s0[0] + 1e-16f);
    o0[1] *= __builtin_amdgcn_rcpf(s0[1] + 1e-16f);
    o0[2] *= __builtin_amdgcn_rcpf(s0[2] + 1e-16f);
    o0[3] *= __builtin_amdgcn_rcpf(s0[3] + 1e-16f);
    o1[0] *= __builtin_amdgcn_rcpf(s1[0] + 1e-16f);
    o1[1] *= __builtin_amdgcn_rcpf(s1[1] + 1e-16f);
    o1[2] *= __builtin_amdgcn_rcpf(s1[2] + 1e-16f);
    o1[3] *= __builtin_amdgcn_rcpf(s1[3] + 1e-16f);
    __builtin_nontemporal_store(o0, &o4[0]);
    __builtin_nontemporal_store(o1, &o4[1]);
}

extern "C" void kernel_launch(void* const* d_in, const int* in_sizes, int n_in,
                              void* d_out, int out_size, void* d_ws, size_t ws_size,
                              hipStream_t stream) {
    const float* x_q  = (const float*)d_in[0];
    const float* x_k  = (const float*)d_in[1];
    const int*   mask = (const int*)d_in[2];
    const float* w_q  = (const float*)d_in[3];
    const float* w_k  = (const float*)d_in[4];
    float* out = (float*)d_out;

    const int M = in_sizes[2] / 2;                 // 320000
    const int N = in_sizes[0] / (BATCH * DHID);    // 10000
    const int Mrows = BATCH * N;                   // 20000

    _Float16* Qh  = (_Float16*)d_ws;
    _Float16* Kh  = Qh  + (size_t)Mrows * DHID;
    _Float16* Wtq = Kh  + (size_t)Mrows * DHID;
    _Float16* Wtk = Wtq + (size_t)DHID * DHID;
    float*    seg = (float*)(Wtk + (size_t)DHID * DHID);

    // P0: transpose W to fp16 + zero seg (one launch)
    prep_kernel<<<dim3(DHID / 32, DHID / 32, 3), dim3(32, 8), 0, stream>>>(
        w_q, w_k, Wtq, Wtk, seg, BATCH * N * NHEAD);

    dim3 ggrid((Mrows + 63) / 64, 1, 2);
    gemm_mfma<<<ggrid, 256, 0, stream>>>(x_q, x_k, Wtq, Wtk, Qh, Kh, Mrows);

    // edge: two half-range dispatches (diagnostic split, work conserved)
    const int Mh = M / 2;
    {
        long waves0 = ((long)Mh + 7) / 8;
        dim3 egrid0((unsigned)((waves0 + 3) / 4), BATCH);
        edge_kernel<<<egrid0, 256, 0, stream>>>(Qh, Kh, mask, out, seg, M, N, 0, Mh);
        long waves1 = ((long)(M - Mh) + 7) / 8;
        dim3 egrid1((unsigned)((waves1 + 3) / 4), BATCH);
        edge_kernel<<<egrid1, 256, 0, stream>>>(Qh, Kh, mask, out, seg, M, N, Mh, M);
    }

    const int BM = BATCH * M;
    norm_kernel<<<(BM + 255) / 256, 256, 0, stream>>>(mask, seg, out, M, N, BM);
}

// Round 13
// 184.207 us; speedup vs baseline: 1.0439x; 1.0439x over previous
//
#include <hip/hip_runtime.h>
#include <hip/hip_bf16.h>
#include <hip/hip_fp16.h>

// Problem constants: B=2, N=10000, M=320000, QD=KD=HD=256, NUM_HEADS=8, dh=32.
#define DHID 256
#define NHEAD 8
#define BATCH 2

typedef _Float16 h8 __attribute__((ext_vector_type(8)));
typedef float f4 __attribute__((ext_vector_type(4)));

// ---------------- P0: W transpose->fp16 (z=0,1) + zero seg (z=2) ----------
__global__ __launch_bounds__(256) void prep_kernel(
    const float* __restrict__ Wq, const float* __restrict__ Wk,
    _Float16* __restrict__ Wtq, _Float16* __restrict__ Wtk,
    float* __restrict__ seg, int segN)
{
    if (blockIdx.z == 2) {
        int idx = (blockIdx.x * 8 + blockIdx.y) * 256 + threadIdx.y * 32 + threadIdx.x;
        for (int i = idx; i < segN; i += 64 * 256) seg[i] = 0.f;
        return;
    }
    const float* W = blockIdx.z ? Wk : Wq;
    _Float16* Wt   = blockIdx.z ? Wtk : Wtq;
    __shared__ float tile[32][33];
    const int tx = threadIdx.x;   // 0..31
    const int ty = threadIdx.y;   // 0..7
    const int n0 = blockIdx.x * 32;
    const int k0 = blockIdx.y * 32;
#pragma unroll
    for (int j = 0; j < 32; j += 8)
        tile[ty + j][tx] = W[(size_t)(k0 + ty + j) * DHID + n0 + tx];
    __syncthreads();
#pragma unroll
    for (int j = 0; j < 32; j += 8)
        Wt[(size_t)(n0 + ty + j) * DHID + k0 + tx] = (_Float16)tile[tx][ty + j];
}

// ---------------- MFMA GEMM, A-stationary, z-loop (tail-kill) -------------
// grid = 313 blocks (one per 64-row tile); each block does Q then K.
// 626-block version ran 512 co-resident + a 114-block second round at ~22%
// device occupancy; 313 blocks all fit in one round -> balanced wall.
__global__ __launch_bounds__(256, 2) void gemm_mfma(
    const float* __restrict__ Xq, const float* __restrict__ Xk,
    const _Float16* __restrict__ Wtq, const _Float16* __restrict__ Wtk,
    _Float16* __restrict__ Qh, _Float16* __restrict__ Kh, int Mrows)
{
    __shared__ _Float16 As[64 * 256];   // 32 KB, [row][k] swizzled
    __shared__ _Float16 Bs[64 * 256];   // 32 KB, [n][k]   swizzled

    const int t    = threadIdx.x;
    const int lane = t & 63;
    const int wave = t >> 6;
    const int rowBase = blockIdx.x * 64;
    const int ar   = wave * 16 + (lane & 15);
    const int quad = lane >> 4;

    for (int z = 0; z < 2; ++z) {
        const float* X     = z ? Xk : Xq;
        const _Float16* Wt = z ? Wtk : Wtq;
        _Float16* C        = z ? Kh : Qh;

        // stage A: 64 rows x 256 k, fp32 -> fp16 (prev iter ended in barrier)
#pragma unroll
        for (int i = 0; i < 8; ++i) {
            int idx = t + i * 256;          // 0..2047
            int row = idx >> 5;
            int c   = idx & 31;
            int grow = rowBase + row;
            f4 v0 = {0,0,0,0}, v1 = {0,0,0,0};
            if (grow < Mrows) {
                const float* p = X + (size_t)grow * DHID + c * 8;
                v0 = *(const f4*)p;
                v1 = *(const f4*)(p + 4);
            }
            h8 hv;
            hv[0]=(_Float16)v0[0]; hv[1]=(_Float16)v0[1]; hv[2]=(_Float16)v0[2]; hv[3]=(_Float16)v0[3];
            hv[4]=(_Float16)v1[0]; hv[5]=(_Float16)v1[1]; hv[6]=(_Float16)v1[2]; hv[7]=(_Float16)v1[3];
            int sc = c ^ (row & 7);
            *(h8*)&As[row * 256 + sc * 8] = hv;
        }

        for (int ct64 = 0; ct64 < 4; ++ct64) {
#pragma unroll
            for (int i = 0; i < 8; ++i) {
                int idx = t + i * 256;
                int n = idx >> 5;
                int c = idx & 31;
                h8 hv = *(const h8*)(Wt + (size_t)(ct64 * 64 + n) * DHID + c * 8);
                int sc = c ^ (n & 7);
                *(h8*)&Bs[n * 256 + sc * 8] = hv;
            }
            __syncthreads();

            f4 acc[4] = {{0,0,0,0},{0,0,0,0},{0,0,0,0},{0,0,0,0}};
#pragma unroll
            for (int kc = 0; kc < 8; ++kc) {            // K chunk of 32
                int ac = (kc * 4 + quad) ^ (ar & 7);
                h8 afrag = *(const h8*)&As[ar * 256 + ac * 8];
#pragma unroll
                for (int ct = 0; ct < 4; ++ct) {
                    int bn = ct * 16 + (lane & 15);
                    int bc = (kc * 4 + quad) ^ (bn & 7);
                    h8 bfrag = *(const h8*)&Bs[bn * 256 + bc * 8];
                    acc[ct] = __builtin_amdgcn_mfma_f32_16x16x32_f16(afrag, bfrag, acc[ct], 0, 0, 0);
                }
            }

#pragma unroll
            for (int ct = 0; ct < 4; ++ct) {
#pragma unroll
                for (int r = 0; r < 4; ++r) {
                    int grow = rowBase + wave * 16 + quad * 4 + r;
                    if (grow < Mrows)
                        C[(size_t)grow * DHID + ct64 * 64 + ct * 16 + (lane & 15)] = (_Float16)acc[ct][r];
                }
            }
            __syncthreads();
        }
    }
}

// ---------------- Edge kernel (r11 layout), fp16 ev intermediate ----------
// lane = (edge-pair half, 16B chunk c); 32 lanes read each row contiguously.
// ev stored as fp16 (halves stream traffic); seg accumulates the QUANTIZED
// value so the final ratio stays consistent.
// Global max subtraction cancels in e/seg -> skipped.
__global__ __launch_bounds__(256, 6) void edge_kernel(
    const _Float16* __restrict__ Qh, const _Float16* __restrict__ Kh,
    const int* __restrict__ mask, _Float16* __restrict__ eh,
    float* __restrict__ seg, int M, int N)
{
    const int lane = threadIdx.x & 63;
    const int wave = threadIdx.x >> 6;
    const int c    = lane & 31;     // 16B chunk within row (c*8 halves)
    const int half = lane >> 5;     // which edge of the pair
    const int h    = c >> 2;        // head of this chunk
    const long e0 = ((long)blockIdx.x * 4 + wave) * 8;
    const int b = blockIdx.y;
    if (e0 >= M) return;

    // lanes 0..7: src of edges e0..e0+7; lanes 8..15: dst
    int idxv = 0;
    {
        long le = e0 + (lane & 7);
        if (le >= M) le = M - 1;
        if (lane < 8)       idxv = mask[le];
        else if (lane < 16) idxv = mask[M + le];
    }

    const _Float16* Qb = Qh + (size_t)b * N * DHID;
    const _Float16* Kb = Kh + (size_t)b * N * DHID;

    int sidx[4], didx[4];
#pragma unroll
    for (int p = 0; p < 4; ++p) {
        sidx[p] = __shfl(idxv, p * 2 + half);
        didx[p] = __shfl(idxv, 8 + p * 2 + half);
    }

    // ---- load phase: 8 instrs, each 2 full rows contiguous ----
    h8 qv[4], kv[4];
#pragma unroll
    for (int p = 0; p < 4; ++p) {
        qv[p] = *(const h8*)(Qb + (size_t)sidx[p] * DHID + c * 8);
        kv[p] = *(const h8*)(Kb + (size_t)didx[p] * DHID + c * 8);
    }

    // ---- compute + emit ----
#pragma unroll
    for (int p = 0; p < 4; ++p) {
        float s = 0.f;
#pragma unroll
        for (int u = 0; u < 8; ++u)
            s += (float)qv[p][u] * (float)kv[p][u];
        s += __shfl_xor(s, 1);
        s += __shfl_xor(s, 2);          // quad c&~3..c|3 now holds head sum
        const long e = e0 + p * 2 + half;
        if ((c & 3) == 0 && e < M) {
            _Float16 evh = (_Float16)expf(s * 0.0625f);   // 1/sqrt(256)
            __builtin_nontemporal_store(evh, &eh[((size_t)b * M + e) * NHEAD + h]);
            atomicAdd(seg + ((size_t)b * N + sidx[p]) * NHEAD + h, (float)evh);
        }
    }
}

// ---------------- Normalize: out = eh / (seg[src] + 1e-16) ----------------
__global__ __launch_bounds__(256) void norm_kernel(
    const int* __restrict__ mask, const float* __restrict__ seg,
    const _Float16* __restrict__ eh, float* __restrict__ out,
    int M, int N, int BM)
{
    int idx = blockIdx.x * 256 + threadIdx.x;   // idx = b*M + e
    if (idx >= BM) return;
    int b = idx / M;
    int e = idx - b * M;
    int src = mask[e];
    const f4* s4 = (const f4*)(seg + ((size_t)b * N + src) * NHEAD);
    f4 s0 = s4[0], s1 = s4[1];
    h8 ev = *(const h8*)(eh + (size_t)idx * NHEAD);
    f4 o0, o1;
    o0[0] = (float)ev[0] * __builtin_amdgcn_rcpf(s0[0] + 1e-16f);
    o0[1] = (float)ev[1] * __builtin_amdgcn_rcpf(s0[1] + 1e-16f);
    o0[2] = (float)ev[2] * __builtin_amdgcn_rcpf(s0[2] + 1e-16f);
    o0[3] = (float)ev[3] * __builtin_amdgcn_rcpf(s0[3] + 1e-16f);
    o1[0] = (float)ev[4] * __builtin_amdgcn_rcpf(s1[0] + 1e-16f);
    o1[1] = (float)ev[5] * __builtin_amdgcn_rcpf(s1[1] + 1e-16f);
    o1[2] = (float)ev[6] * __builtin_amdgcn_rcpf(s1[2] + 1e-16f);
    o1[3] = (float)ev[7] * __builtin_amdgcn_rcpf(s1[3] + 1e-16f);
    f4* o4 = (f4*)(out + (size_t)idx * NHEAD);
    __builtin_nontemporal_store(o0, &o4[0]);
    __builtin_nontemporal_store(o1, &o4[1]);
}

extern "C" void kernel_launch(void* const* d_in, const int* in_sizes, int n_in,
                              void* d_out, int out_size, void* d_ws, size_t ws_size,
                              hipStream_t stream) {
    const float* x_q  = (const float*)d_in[0];
    const float* x_k  = (const float*)d_in[1];
    const int*   mask = (const int*)d_in[2];
    const float* w_q  = (const float*)d_in[3];
    const float* w_k  = (const float*)d_in[4];
    float* out = (float*)d_out;

    const int M = in_sizes[2] / 2;                 // 320000
    const int N = in_sizes[0] / (BATCH * DHID);    // 10000
    const int Mrows = BATCH * N;                   // 20000

    _Float16* Qh  = (_Float16*)d_ws;
    _Float16* Kh  = Qh  + (size_t)Mrows * DHID;
    _Float16* Wtq = Kh  + (size_t)Mrows * DHID;
    _Float16* Wtk = Wtq + (size_t)DHID * DHID;
    float*    seg = (float*)(Wtk + (size_t)DHID * DHID);
    _Float16* eh  = (_Float16*)(seg + (size_t)BATCH * N * NHEAD);

    // P0: transpose W to fp16 + zero seg (one launch)
    prep_kernel<<<dim3(DHID / 32, DHID / 32, 3), dim3(32, 8), 0, stream>>>(
        w_q, w_k, Wtq, Wtk, seg, BATCH * N * NHEAD);

    // GEMM: 313 blocks, z-loop inside (no second dispatch round)
    gemm_mfma<<<dim3((Mrows + 63) / 64), 256, 0, stream>>>(
        x_q, x_k, Wtq, Wtk, Qh, Kh, Mrows);

    // edge: 8 edges per wave, 4 waves per block
    long waves = (M + 7) / 8;
    dim3 egrid((unsigned)((waves + 3) / 4), BATCH);
    edge_kernel<<<egrid, 256, 0, stream>>>(Qh, Kh, mask, eh, seg, M, N);

    const int BM = BATCH * M;
    norm_kernel<<<(BM + 255) / 256, 256, 0, stream>>>(mask, seg, eh, out, M, N, BM);
}

// Round 14
// 181.375 us; speedup vs baseline: 1.0602x; 1.0156x over previous
//
#include <hip/hip_runtime.h>
#include <hip/hip_bf16.h>
#include <hip/hip_fp16.h>

// Problem constants: B=2, N=10000, M=320000, QD=KD=HD=256, NUM_HEADS=8, dh=32.
#define DHID 256
#define NHEAD 8
#define BATCH 2

typedef _Float16 h8 __attribute__((ext_vector_type(8)));
typedef float f4 __attribute__((ext_vector_type(4)));

// ---------------- P0: W transpose->fp16 only (seg-zero moved to gemm) -----
__global__ __launch_bounds__(256) void prep_kernel(
    const float* __restrict__ Wq, const float* __restrict__ Wk,
    _Float16* __restrict__ Wtq, _Float16* __restrict__ Wtk)
{
    const float* W = blockIdx.z ? Wk : Wq;
    _Float16* Wt   = blockIdx.z ? Wtk : Wtq;
    __shared__ float tile[32][33];
    const int tx = threadIdx.x;   // 0..31
    const int ty = threadIdx.y;   // 0..7
    const int n0 = blockIdx.x * 32;
    const int k0 = blockIdx.y * 32;
#pragma unroll
    for (int j = 0; j < 32; j += 8)
        tile[ty + j][tx] = W[(size_t)(k0 + ty + j) * DHID + n0 + tx];
    __syncthreads();
#pragma unroll
    for (int j = 0; j < 32; j += 8)
        Wt[(size_t)(n0 + ty + j) * DHID + k0 + tx] = (_Float16)tile[tx][ty + j];
}

// ---------------- MFMA GEMM, A-stationary (626-block r11 winner) ----------
// Blocks x >= nx (z==0) zero seg instead (gemm never reads seg -> safe).
__global__ __launch_bounds__(256, 2) void gemm_mfma(
    const float* __restrict__ Xq, const float* __restrict__ Xk,
    const _Float16* __restrict__ Wtq, const _Float16* __restrict__ Wtk,
    _Float16* __restrict__ Qh, _Float16* __restrict__ Kh,
    float* __restrict__ seg, int segN, int nx, int Mrows)
{
    const int t = threadIdx.x;
    if ((int)blockIdx.x >= nx) {
        if (blockIdx.z == 0) {       // seg-zero side job
            int base = ((int)blockIdx.x - nx) * 256 + t;
            f4 z = {0.f, 0.f, 0.f, 0.f};
            for (int i = base; i < segN / 4; i += 8 * 256)
                ((f4*)seg)[i] = z;
        }
        return;
    }

    const float* X       = blockIdx.z ? Xk : Xq;
    const _Float16* Wt   = blockIdx.z ? Wtk : Wtq;
    _Float16* C          = blockIdx.z ? Kh : Qh;

    __shared__ _Float16 As[64 * 256];   // 32 KB, [row][k] swizzled
    __shared__ _Float16 Bs[64 * 256];   // 32 KB, [n][k]   swizzled

    const int lane = t & 63;
    const int wave = t >> 6;
    const int rowBase = blockIdx.x * 64;

#pragma unroll
    for (int i = 0; i < 8; ++i) {
        int idx = t + i * 256;          // 0..2047
        int row = idx >> 5;
        int c   = idx & 31;
        int grow = rowBase + row;
        f4 v0 = {0,0,0,0}, v1 = {0,0,0,0};
        if (grow < Mrows) {
            const float* p = X + (size_t)grow * DHID + c * 8;
            v0 = *(const f4*)p;
            v1 = *(const f4*)(p + 4);
        }
        h8 hv;
        hv[0]=(_Float16)v0[0]; hv[1]=(_Float16)v0[1]; hv[2]=(_Float16)v0[2]; hv[3]=(_Float16)v0[3];
        hv[4]=(_Float16)v1[0]; hv[5]=(_Float16)v1[1]; hv[6]=(_Float16)v1[2]; hv[7]=(_Float16)v1[3];
        int sc = c ^ (row & 7);
        *(h8*)&As[row * 256 + sc * 8] = hv;
    }

    const int ar   = wave * 16 + (lane & 15);
    const int quad = lane >> 4;

    for (int ct64 = 0; ct64 < 4; ++ct64) {
#pragma unroll
        for (int i = 0; i < 8; ++i) {
            int idx = t + i * 256;
            int n = idx >> 5;
            int c = idx & 31;
            h8 hv = *(const h8*)(Wt + (size_t)(ct64 * 64 + n) * DHID + c * 8);
            int sc = c ^ (n & 7);
            *(h8*)&Bs[n * 256 + sc * 8] = hv;
        }
        __syncthreads();

        f4 acc[4] = {{0,0,0,0},{0,0,0,0},{0,0,0,0},{0,0,0,0}};
#pragma unroll
        for (int kc = 0; kc < 8; ++kc) {            // K chunk of 32
            int ac = (kc * 4 + quad) ^ (ar & 7);
            h8 afrag = *(const h8*)&As[ar * 256 + ac * 8];
#pragma unroll
            for (int ct = 0; ct < 4; ++ct) {
                int bn = ct * 16 + (lane & 15);
                int bc = (kc * 4 + quad) ^ (bn & 7);
                h8 bfrag = *(const h8*)&Bs[bn * 256 + bc * 8];
                acc[ct] = __builtin_amdgcn_mfma_f32_16x16x32_f16(afrag, bfrag, acc[ct], 0, 0, 0);
            }
        }

#pragma unroll
        for (int ct = 0; ct < 4; ++ct) {
#pragma unroll
            for (int r = 0; r < 4; ++r) {
                int grow = rowBase + wave * 16 + quad * 4 + r;
                if (grow < Mrows)
                    C[(size_t)grow * DHID + ct64 * 64 + ct * 16 + (lane & 15)] = (_Float16)acc[ct][r];
            }
        }
        __syncthreads();
    }
}

// ---------------- Edge kernel (r11 layout), fp16 ev intermediate ----------
// lane = (edge-pair half, 16B chunk c); 32 lanes read each row contiguously.
// ev stored as fp16; seg accumulates the QUANTIZED value (ratio-consistent).
// Global max subtraction cancels in e/seg -> skipped.
// Edge ~64us is structural: per-CU L2-miss concurrency is HW-capped (~30
// lines @ ~600cyc LLC latency -> 3.9 TB/s fill); 4 different layouts all
// land 64-66us with FETCH ~204 MB.
__global__ __launch_bounds__(256, 6) void edge_kernel(
    const _Float16* __restrict__ Qh, const _Float16* __restrict__ Kh,
    const int* __restrict__ mask, _Float16* __restrict__ eh,
    float* __restrict__ seg, int M, int N)
{
    const int lane = threadIdx.x & 63;
    const int wave = threadIdx.x >> 6;
    const int c    = lane & 31;     // 16B chunk within row (c*8 halves)
    const int half = lane >> 5;     // which edge of the pair
    const int h    = c >> 2;        // head of this chunk
    const long e0 = ((long)blockIdx.x * 4 + wave) * 8;
    const int b = blockIdx.y;
    if (e0 >= M) return;

    // lanes 0..7: src of edges e0..e0+7; lanes 8..15: dst
    int idxv = 0;
    {
        long le = e0 + (lane & 7);
        if (le >= M) le = M - 1;
        if (lane < 8)       idxv = mask[le];
        else if (lane < 16) idxv = mask[M + le];
    }

    const _Float16* Qb = Qh + (size_t)b * N * DHID;
    const _Float16* Kb = Kh + (size_t)b * N * DHID;

    int sidx[4], didx[4];
#pragma unroll
    for (int p = 0; p < 4; ++p) {
        sidx[p] = __shfl(idxv, p * 2 + half);
        didx[p] = __shfl(idxv, 8 + p * 2 + half);
    }

    // ---- load phase: 8 instrs, each 2 full rows contiguous ----
    h8 qv[4], kv[4];
#pragma unroll
    for (int p = 0; p < 4; ++p) {
        qv[p] = *(const h8*)(Qb + (size_t)sidx[p] * DHID + c * 8);
        kv[p] = *(const h8*)(Kb + (size_t)didx[p] * DHID + c * 8);
    }

    // ---- compute + emit ----
#pragma unroll
    for (int p = 0; p < 4; ++p) {
        float s = 0.f;
#pragma unroll
        for (int u = 0; u < 8; ++u)
            s += (float)qv[p][u] * (float)kv[p][u];
        s += __shfl_xor(s, 1);
        s += __shfl_xor(s, 2);          // quad c&~3..c|3 now holds head sum
        const long e = e0 + p * 2 + half;
        if ((c & 3) == 0 && e < M) {
            _Float16 evh = (_Float16)expf(s * 0.0625f);   // 1/sqrt(256)
            __builtin_nontemporal_store(evh, &eh[((size_t)b * M + e) * NHEAD + h]);
            atomicAdd(seg + ((size_t)b * N + sidx[p]) * NHEAD + h, (float)evh);
        }
    }
}

// ---------------- Normalize: out = eh / (seg[src] + 1e-16) ----------------
__global__ __launch_bounds__(256) void norm_kernel(
    const int* __restrict__ mask, const float* __restrict__ seg,
    const _Float16* __restrict__ eh, float* __restrict__ out,
    int M, int N, int BM)
{
    int idx = blockIdx.x * 256 + threadIdx.x;   // idx = b*M + e
    if (idx >= BM) return;
    int b = idx / M;
    int e = idx - b * M;
    int src = mask[e];
    const f4* s4 = (const f4*)(seg + ((size_t)b * N + src) * NHEAD);
    f4 s0 = s4[0], s1 = s4[1];
    h8 ev = *(const h8*)(eh + (size_t)idx * NHEAD);
    f4 o0, o1;
    o0[0] = (float)ev[0] * __builtin_amdgcn_rcpf(s0[0] + 1e-16f);
    o0[1] = (float)ev[1] * __builtin_amdgcn_rcpf(s0[1] + 1e-16f);
    o0[2] = (float)ev[2] * __builtin_amdgcn_rcpf(s0[2] + 1e-16f);
    o0[3] = (float)ev[3] * __builtin_amdgcn_rcpf(s0[3] + 1e-16f);
    o1[0] = (float)ev[4] * __builtin_amdgcn_rcpf(s1[0] + 1e-16f);
    o1[1] = (float)ev[5] * __builtin_amdgcn_rcpf(s1[1] + 1e-16f);
    o1[2] = (float)ev[6] * __builtin_amdgcn_rcpf(s1[2] + 1e-16f);
    o1[3] = (float)ev[7] * __builtin_amdgcn_rcpf(s1[3] + 1e-16f);
    f4* o4 = (f4*)(out + (size_t)idx * NHEAD);
    __builtin_nontemporal_store(o0, &o4[0]);
    __builtin_nontemporal_store(o1, &o4[1]);
}

extern "C" void kernel_launch(void* const* d_in, const int* in_sizes, int n_in,
                              void* d_out, int out_size, void* d_ws, size_t ws_size,
                              hipStream_t stream) {
    const float* x_q  = (const float*)d_in[0];
    const float* x_k  = (const float*)d_in[1];
    const int*   mask = (const int*)d_in[2];
    const float* w_q  = (const float*)d_in[3];
    const float* w_k  = (const float*)d_in[4];
    float* out = (float*)d_out;

    const int M = in_sizes[2] / 2;                 // 320000
    const int N = in_sizes[0] / (BATCH * DHID);    // 10000
    const int Mrows = BATCH * N;                   // 20000
    const int segN  = BATCH * N * NHEAD;

    _Float16* Qh  = (_Float16*)d_ws;
    _Float16* Kh  = Qh  + (size_t)Mrows * DHID;
    _Float16* Wtq = Kh  + (size_t)Mrows * DHID;
    _Float16* Wtk = Wtq + (size_t)DHID * DHID;
    float*    seg = (float*)(Wtk + (size_t)DHID * DHID);
    _Float16* eh  = (_Float16*)(seg + (size_t)segN);

    // P0: transpose W to fp16 (seg-zero folded into gemm's spare blocks)
    prep_kernel<<<dim3(DHID / 32, DHID / 32, 2), dim3(32, 8), 0, stream>>>(
        w_q, w_k, Wtq, Wtk);

    // GEMM: 626 blocks + 8 seg-zero blocks on z=0
    const int nx = (Mrows + 63) / 64;              // 313
    gemm_mfma<<<dim3(nx + 8, 1, 2), 256, 0, stream>>>(
        x_q, x_k, Wtq, Wtk, Qh, Kh, seg, segN, nx, Mrows);

    // edge: 8 edges per wave, 4 waves per block
    long waves = (M + 7) / 8;
    dim3 egrid((unsigned)((waves + 3) / 4), BATCH);
    edge_kernel<<<egrid, 256, 0, stream>>>(Qh, Kh, mask, eh, seg, M, N);

    const int BM = BATCH * M;
    norm_kernel<<<(BM + 255) / 256, 256, 0, stream>>>(mask, seg, eh, out, M, N, BM);
}